// Round 3
// baseline (252.553 us; speedup 1.0000x reference)
//
#include <hip/hip_runtime.h>
#include <stdint.h>

#define NTREES 8
#define NNODES 5
#define CC 16
#define BB 8
#define HH 224
#define WW 224
#define NEGF (-1e30f)
#define LN2F 0.6931471805599453f

struct Forest { int par[NTREES * NNODES]; };

// ---------------------------------------------------------------------------
// Host-side bit-exact reproduction of np.random.default_rng(0) forest
// (verified absmax 0.0 vs numpy in rounds 1-2 — do not touch).
// ---------------------------------------------------------------------------
namespace nprng {

struct Pcg {
  __uint128_t state, inc;
  int has_uint32;
  uint32_t uinteger;
};

static inline __uint128_t pcg_mult() {
  return (((__uint128_t)0x2360ED051FC65DA4ULL) << 64) | 0x4385DF649FCCF645ULL;
}

static inline void pcg_step(Pcg& s) { s.state = s.state * pcg_mult() + s.inc; }

static inline uint64_t pcg_next64(Pcg& s) {
  pcg_step(s);
  uint64_t xored = (uint64_t)(s.state >> 64) ^ (uint64_t)s.state;
  unsigned rot = (unsigned)(s.state >> 122);
  return (xored >> rot) | (xored << ((64u - rot) & 63u));
}

static inline uint32_t pcg_next32(Pcg& s) {
  if (s.has_uint32) { s.has_uint32 = 0; return s.uinteger; }
  uint64_t n = pcg_next64(s);
  s.has_uint32 = 1;
  s.uinteger = (uint32_t)(n >> 32);
  return (uint32_t)n;
}

static inline uint32_t lemire32(Pcg& s, uint32_t rng) {
  const uint32_t rng_excl = rng + 1u;
  uint64_t m = (uint64_t)pcg_next32(s) * (uint64_t)rng_excl;
  uint32_t leftover = (uint32_t)m;
  if (leftover < rng_excl) {
    const uint32_t threshold = (uint32_t)((0xFFFFFFFFu - rng) % rng_excl);
    while (leftover < threshold) {
      m = (uint64_t)pcg_next32(s) * (uint64_t)rng_excl;
      leftover = (uint32_t)m;
    }
  }
  return (uint32_t)(m >> 32);
}

static void make_forest(Forest& f) {
  const uint32_t INIT_A = 0x43b0d7e5u, MULT_A = 0x931e8875u;
  const uint32_t INIT_B = 0x8b51f9ddu, MULT_B = 0x58f38dedu;
  const uint32_t MIX_L  = 0xca01f9ddu, MIX_R  = 0x4973f715u;
  uint32_t pool[4];
  uint32_t hc = INIT_A;
  auto hashmix = [&](uint32_t v) -> uint32_t {
    v ^= hc; hc *= MULT_A; v *= hc; v ^= v >> 16; return v;
  };
  auto mix = [&](uint32_t x, uint32_t y) -> uint32_t {
    uint32_t r = MIX_L * x - MIX_R * y; r ^= r >> 16; return r;
  };
  pool[0] = hashmix(0u);
  for (int i = 1; i < 4; ++i) pool[i] = hashmix(0u);
  for (int is = 0; is < 4; ++is)
    for (int id = 0; id < 4; ++id)
      if (is != id) pool[id] = mix(pool[id], hashmix(pool[is]));
  uint32_t st32[8];
  uint32_t hb = INIT_B;
  for (int i = 0; i < 8; ++i) {
    uint32_t dv = pool[i & 3];
    dv ^= hb; hb *= MULT_B; dv *= hb; dv ^= dv >> 16;
    st32[i] = dv;
  }
  uint64_t w64[4];
  for (int i = 0; i < 4; ++i)
    w64[i] = (uint64_t)st32[2 * i] | ((uint64_t)st32[2 * i + 1] << 32);

  __uint128_t initstate = (((__uint128_t)w64[0]) << 64) | w64[1];
  __uint128_t initseq   = (((__uint128_t)w64[2]) << 64) | w64[3];
  Pcg s;
  s.state = 0; s.inc = (initseq << 1) | 1;
  pcg_step(s);
  s.state += initstate;
  pcg_step(s);
  s.has_uint32 = 0; s.uinteger = 0;

  for (int t = 0; t < NTREES; ++t) {
    f.par[t * NNODES + 0] = -1;
    for (int i = 1; i < NNODES; ++i) {
      uint32_t rng = (uint32_t)(i - 1);
      f.par[t * NNODES + i] = (rng == 0) ? 0 : (int)lemire32(s, rng);
    }
  }
}

}  // namespace nprng

// ---------------------------------------------------------------------------
// DPP helpers. old = -inf (max identity) so GCNDPPCombine can fuse the
// update_dpp mov into the consuming v_max_f32 (drops a v_mov per step).
// Data sentinels remain -1e30 (match reference); -inf only appears as the
// fill value inside max chains, never feeds an add.
// ---------------------------------------------------------------------------
#define NINF_BITS 0xff800000

template <int ctrl, int rm>
__device__ __forceinline__ float dpp_ninf(float x) {
  int r = __builtin_amdgcn_update_dpp(
      (int)NINF_BITS, __builtin_bit_cast(int, x), ctrl, rm, 0xf, false);
  return __builtin_bit_cast(float, r);
}

// Inclusive 64-lane max-scan: 6 dpp-max ops.
__device__ __forceinline__ float wave_incl_maxscan(float t) {
  t = fmaxf(t, dpp_ninf<0x111, 0xf>(t));  // row_shr:1
  t = fmaxf(t, dpp_ninf<0x112, 0xf>(t));  // row_shr:2
  t = fmaxf(t, dpp_ninf<0x114, 0xf>(t));  // row_shr:4
  t = fmaxf(t, dpp_ninf<0x118, 0xf>(t));  // row_shr:8
  t = fmaxf(t, dpp_ninf<0x142, 0xa>(t));  // row_bcast15 -> rows 1,3
  t = fmaxf(t, dpp_ninf<0x143, 0xc>(t));  // row_bcast31 -> rows 2,3
  return t;
}

// Shift whole wave right by 1 lane, -inf into lane 0.
__device__ __forceinline__ float wshr1(float t) {
  return dpp_ninf<0x138, 0xf>(t);  // wave_shr:1
}

#define ADD2(d, s) { (d).x += (s).x; (d).y += (s).y; }

// ---------------------------------------------------------------------------
// 2 waves per (tree,b,c) unit; 128-thread blocks; 2048 waves = 2 waves/SIMD.
// Wave 0 owns cols 0..127 (2/lane), wave 1 owns cols 128..223 (lanes 0..47).
// Cross-wave coupling is one-row-lagged: wave0 publishes per-node boundary
// maxes M_j(h,127) to LDS (parity double-buffered); wave1 folds them into its
// pm at row h+1. Exact by induction on M(h,w)=max(M(h-1,w), rowprefix(h,<=w)).
// One __syncthreads per row.
// ---------------------------------------------------------------------------
__global__ __launch_bounds__(128) void fis_kernel(const float* __restrict__ x,
                                                  const float* __restrict__ alphas,
                                                  float* __restrict__ out,
                                                  Forest f) {
  const int tid  = threadIdx.x;
  const int lane = tid & 63;
  const int wv   = tid >> 6;  // 0 or 1
  const int blk  = blockIdx.x;
  const int t    = blk >> 7;   // tree (blocks 128 apart share x-plane -> same XCD)
  const int bc   = blk & 127;  // b*16 + c
  const int c    = bc & (CC - 1);
  const int b    = bc >> 4;

  const float* __restrict__ xp = x + (size_t)bc * (HH * WW);

  float asum = 0.f;
#pragma unroll
  for (int i = 0; i < NNODES; ++i) asum += alphas[(t * NNODES + i) * CC + c];

  const int p2 = f.par[t * NNODES + 2];
  const int p3 = f.par[t * NNODES + 3];
  const int p4 = f.par[t * NNODES + 4];
  // p1 is always 0.

  __shared__ __align__(16) float carry[2][4];  // [row parity][node-1]
  __shared__ float red[2];
  if (tid < 8) ((float*)carry)[tid] = NEGF;
  __syncthreads();

  const int  col0 = wv * 128 + lane * 2;
  const bool act  = (col0 < WW);
  const float* __restrict__ cp = xp + col0;

  const float2 neg2 = make_float2(NEGF, NEGF);
  float2 pm1 = neg2, pm2 = neg2, pm3 = neg2, pm4 = neg2, racc = neg2;

  // Prefetch pipeline depth 3.
  float2 xa = neg2, xb = neg2, xc = neg2;
  if (act) {
    xa = *(const float2*)(cp);
    xb = *(const float2*)(cp + WW);
    xc = *(const float2*)(cp + 2 * WW);
  }

  auto scanupd = [&](const float2& v, float2& pm) {
    float l1 = fmaxf(v.x, v.y);
    float q  = wave_incl_maxscan(l1);   // inclusive prefix over this wave
    float e  = wshr1(q);                // exclusive
    pm.x = fmaxf(pm.x, fmaxf(e, v.x));
    pm.y = fmaxf(pm.y, q);
  };

#pragma unroll 2
  for (int h = 0; h < HH; ++h) {
    float2 xn = neg2;
    if (h + 3 < HH && act)
      xn = *(const float2*)(cp + (size_t)(h + 3) * WW);

    // --- carry from left wave (row h-1 data; slot parity (h-1)&1) ---
    float4 C = *(const float4*)carry[(h + 1) & 1];
    if (wv == 0) C = make_float4(NEGF, NEGF, NEGF, NEGF);  // wave-uniform

    // Fold carry into pm: pm now equals global M(h-1, w) for own cols.
    pm1.x = fmaxf(pm1.x, C.x); pm1.y = fmaxf(pm1.y, C.x);
    pm2.x = fmaxf(pm2.x, C.y); pm2.y = fmaxf(pm2.y, C.y);
    pm3.x = fmaxf(pm3.x, C.z); pm3.y = fmaxf(pm3.y, C.z);
    pm4.x = fmaxf(pm4.x, C.w); pm4.y = fmaxf(pm4.y, C.w);

    // --- xv = log2(1 + relu(x)) (alphas factored out) ---
    float2 xv;
    xv.x = act ? __log2f(1.0f + fmaxf(xa.x, 0.0f)) : NEGF;
    xv.y = act ? __log2f(1.0f + fmaxf(xa.y, 0.0f)) : NEGF;

    // --- s_j(w) = M_j(h-1, w-1); lane0 hole takes carry ---
    float2 s1 = make_float2(fmaxf(wshr1(pm1.y), C.x), pm1.x);
    float2 s2 = make_float2(fmaxf(wshr1(pm2.y), C.y), pm2.x);
    float2 s3 = make_float2(fmaxf(wshr1(pm3.y), C.z), pm3.x);
    float2 s4 = make_float2(fmaxf(wshr1(pm4.y), C.w), pm4.x);

    float2 v0 = xv, v1 = xv, v2 = xv, v3 = xv, v4 = xv;
    (void)v4;

    if      (p4 == 0) ADD2(v0, s4) else if (p4 == 1) ADD2(v1, s4)
    else if (p4 == 2) ADD2(v2, s4) else              ADD2(v3, s4);
    if      (p3 == 0) ADD2(v0, s3) else if (p3 == 1) ADD2(v1, s3)
    else              ADD2(v2, s3);
    if      (p2 == 0) ADD2(v0, s2) else              ADD2(v1, s2);
    ADD2(v0, s1);  // p1 == 0 always

    scanupd(v1, pm1);
    scanupd(v2, pm2);
    scanupd(v3, pm3);
    scanupd(v4, pm4);

    racc.x = fmaxf(racc.x, v0.x);
    racc.y = fmaxf(racc.y, v0.y);

    // --- wave0 lane63 publishes boundary maxes M_j(h,127) ---
    if (tid == 63)
      *(float4*)carry[h & 1] = make_float4(pm1.y, pm2.y, pm3.y, pm4.y);

    __syncthreads();

    xa = xb; xb = xc; xc = xn;
  }

  float m = fmaxf(racc.x, racc.y);
#pragma unroll
  for (int d = 1; d < 64; d <<= 1) m = fmaxf(m, __shfl_xor(m, d));
  if (lane == 0) red[wv] = m;
  __syncthreads();
  if (tid == 0)
    out[((size_t)b * NTREES + t) * CC + c] =
        expm1f(fmaf(fmaxf(red[0], red[1]), LN2F, asum));
}

extern "C" void kernel_launch(void* const* d_in, const int* in_sizes, int n_in,
                              void* d_out, int out_size, void* d_ws, size_t ws_size,
                              hipStream_t stream) {
  const float* x      = (const float*)d_in[0];
  const float* alphas = (const float*)d_in[1];
  float* out          = (float*)d_out;

  Forest f;
  nprng::make_forest(f);  // deterministic; same every call (graph-capture safe)

  dim3 grid(BB * CC * NTREES);  // 1024 blocks x 2 waves = 2 waves/SIMD
  dim3 block(128);
  hipLaunchKernelGGL(fis_kernel, grid, block, 0, stream, x, alphas, out, f);
}

// Round 4
// 204.390 us; speedup vs baseline: 1.2356x; 1.2356x over previous
//
#include <hip/hip_runtime.h>
#include <stdint.h>

#define NTREES 8
#define NNODES 5
#define CC 16
#define BB 8
#define HH 224
#define WW 224
#define NEGF (-1e30f)
#define LN2F 0.6931471805599453f

struct Forest { int par[NTREES * NNODES]; };

// ---------------------------------------------------------------------------
// Host-side bit-exact reproduction of np.random.default_rng(0) forest
// (verified absmax 0.0 vs numpy in rounds 1-3 — do not touch).
// ---------------------------------------------------------------------------
namespace nprng {

struct Pcg {
  __uint128_t state, inc;
  int has_uint32;
  uint32_t uinteger;
};

static inline __uint128_t pcg_mult() {
  return (((__uint128_t)0x2360ED051FC65DA4ULL) << 64) | 0x4385DF649FCCF645ULL;
}

static inline void pcg_step(Pcg& s) { s.state = s.state * pcg_mult() + s.inc; }

static inline uint64_t pcg_next64(Pcg& s) {
  pcg_step(s);
  uint64_t xored = (uint64_t)(s.state >> 64) ^ (uint64_t)s.state;
  unsigned rot = (unsigned)(s.state >> 122);
  return (xored >> rot) | (xored << ((64u - rot) & 63u));
}

static inline uint32_t pcg_next32(Pcg& s) {
  if (s.has_uint32) { s.has_uint32 = 0; return s.uinteger; }
  uint64_t n = pcg_next64(s);
  s.has_uint32 = 1;
  s.uinteger = (uint32_t)(n >> 32);
  return (uint32_t)n;
}

static inline uint32_t lemire32(Pcg& s, uint32_t rng) {
  const uint32_t rng_excl = rng + 1u;
  uint64_t m = (uint64_t)pcg_next32(s) * (uint64_t)rng_excl;
  uint32_t leftover = (uint32_t)m;
  if (leftover < rng_excl) {
    const uint32_t threshold = (uint32_t)((0xFFFFFFFFu - rng) % rng_excl);
    while (leftover < threshold) {
      m = (uint64_t)pcg_next32(s) * (uint64_t)rng_excl;
      leftover = (uint32_t)m;
    }
  }
  return (uint32_t)(m >> 32);
}

static void make_forest(Forest& f) {
  const uint32_t INIT_A = 0x43b0d7e5u, MULT_A = 0x931e8875u;
  const uint32_t INIT_B = 0x8b51f9ddu, MULT_B = 0x58f38dedu;
  const uint32_t MIX_L  = 0xca01f9ddu, MIX_R  = 0x4973f715u;
  uint32_t pool[4];
  uint32_t hc = INIT_A;
  auto hashmix = [&](uint32_t v) -> uint32_t {
    v ^= hc; hc *= MULT_A; v *= hc; v ^= v >> 16; return v;
  };
  auto mix = [&](uint32_t x, uint32_t y) -> uint32_t {
    uint32_t r = MIX_L * x - MIX_R * y; r ^= r >> 16; return r;
  };
  pool[0] = hashmix(0u);
  for (int i = 1; i < 4; ++i) pool[i] = hashmix(0u);
  for (int is = 0; is < 4; ++is)
    for (int id = 0; id < 4; ++id)
      if (is != id) pool[id] = mix(pool[id], hashmix(pool[is]));
  uint32_t st32[8];
  uint32_t hb = INIT_B;
  for (int i = 0; i < 8; ++i) {
    uint32_t dv = pool[i & 3];
    dv ^= hb; hb *= MULT_B; dv *= hb; dv ^= dv >> 16;
    st32[i] = dv;
  }
  uint64_t w64[4];
  for (int i = 0; i < 4; ++i)
    w64[i] = (uint64_t)st32[2 * i] | ((uint64_t)st32[2 * i + 1] << 32);

  __uint128_t initstate = (((__uint128_t)w64[0]) << 64) | w64[1];
  __uint128_t initseq   = (((__uint128_t)w64[2]) << 64) | w64[3];
  Pcg s;
  s.state = 0; s.inc = (initseq << 1) | 1;
  pcg_step(s);
  s.state += initstate;
  pcg_step(s);
  s.has_uint32 = 0; s.uinteger = 0;

  for (int t = 0; t < NTREES; ++t) {
    f.par[t * NNODES + 0] = -1;
    for (int i = 1; i < NNODES; ++i) {
      uint32_t rng = (uint32_t)(i - 1);
      f.par[t * NNODES + i] = (rng == 0) ? 0 : (int)lemire32(s, rng);
    }
  }
}

}  // namespace nprng

// ---------------------------------------------------------------------------
// DPP helpers.
// wshr1: whole-wave shift right by 1, -inf into lane 0 (builtin update_dpp —
// compiler handles its hazards).
// SCAN_*: in-place v_max_f32_dpp scan steps via asm (1 inst each). dst==src0,
// bound_ctrl off => lanes with invalid DPP source keep their old value, which
// is exactly inclusive-scan semantics. Stage-major emission (all 4 nodes per
// stage, volatile => program-order preserved) spaces dependent DPP ops >=3
// instructions apart, satisfying the 2-wait-state VALU->DPP-read hazard.
// DPP_FENCE: s_nop 1 pinned by fake read-write of q1..q4 — guards the
// boundaries between compiler code and the asm scan block.
// ---------------------------------------------------------------------------
#define NINF_BITS 0xff800000

template <int ctrl, int rm>
__device__ __forceinline__ float dpp_ninf(float x) {
  int r = __builtin_amdgcn_update_dpp(
      (int)NINF_BITS, __builtin_bit_cast(int, x), ctrl, rm, 0xf, false);
  return __builtin_bit_cast(float, r);
}

__device__ __forceinline__ float wshr1(float t) {
  return dpp_ninf<0x138, 0xf>(t);  // wave_shr:1
}

#define SCAN_SHR(q, N) \
  asm volatile("v_max_f32_dpp %0, %0, %0 row_shr:" #N \
               " row_mask:0xf bank_mask:0xf" : "+v"(q))
#define SCAN_B15(q) \
  asm volatile("v_max_f32_dpp %0, %0, %0 row_bcast:15" \
               " row_mask:0xa bank_mask:0xf" : "+v"(q))
#define SCAN_B31(q) \
  asm volatile("v_max_f32_dpp %0, %0, %0 row_bcast:31" \
               " row_mask:0xc bank_mask:0xf" : "+v"(q))
#define DPP_FENCE(a, b, c, d) \
  asm volatile("s_nop 1" : "+v"(a), "+v"(b), "+v"(c), "+v"(d))

#define ADD4(d, s) { (d).x += (s).x; (d).y += (s).y; (d).z += (s).z; (d).w += (s).w; }

// ---------------------------------------------------------------------------
// Precompute: xv = log2(1 + relu(x)) once per plane (reused by 8 trees).
// ---------------------------------------------------------------------------
__global__ __launch_bounds__(256) void xv_kernel(const float* __restrict__ x,
                                                 float* __restrict__ xv, int n4) {
  int i = blockIdx.x * 256 + threadIdx.x;
  if (i < n4) {
    float4 v = ((const float4*)x)[i];
    v.x = __log2f(1.0f + fmaxf(v.x, 0.0f));
    v.y = __log2f(1.0f + fmaxf(v.y, 0.0f));
    v.z = __log2f(1.0f + fmaxf(v.z, 0.0f));
    v.w = __log2f(1.0f + fmaxf(v.w, 0.0f));
    ((float4*)xv)[i] = v;
  }
}

// ---------------------------------------------------------------------------
// One wave per (tree,b,c). Alphas factored out; DP on log2-units; epilogue
// expm1(asum + ln2*m). Swizzle: blocks 128 apart share an x-plane -> same XCD.
// PRE: read precomputed xv from workspace; else compute logs inline.
// ---------------------------------------------------------------------------
template <bool PRE>
__global__ __launch_bounds__(64) void fis_kernel(const float* __restrict__ src,
                                                 const float* __restrict__ alphas,
                                                 float* __restrict__ out,
                                                 Forest f) {
  const int lane = threadIdx.x;
  const int blk  = blockIdx.x;
  const int t    = blk >> 7;
  const int bc   = blk & 127;
  const int c    = bc & (CC - 1);
  const int b    = bc >> 4;

  const float* __restrict__ xp = src + (size_t)bc * (HH * WW);

  float asum = 0.f;
#pragma unroll
  for (int i = 0; i < NNODES; ++i) asum += alphas[(t * NNODES + i) * CC + c];

  const int p2 = f.par[t * NNODES + 2];
  const int p3 = f.par[t * NNODES + 3];
  const int p4 = f.par[t * NNODES + 4];
  // p1 is always 0.

  const int  w0  = lane * 4;
  const bool act = (w0 < WW);
  const float* __restrict__ cp = xp + w0;

  const float4 neg4 = make_float4(NEGF, NEGF, NEGF, NEGF);
  float4 pm1 = neg4, pm2 = neg4, pm3 = neg4, pm4 = neg4, racc = neg4;

  // Prefetch pipeline depth 3.
  float4 xa = neg4, xb = neg4, xc = neg4;
  if (act) {
    xa = *(const float4*)(cp);
    xb = *(const float4*)(cp + WW);
    xc = *(const float4*)(cp + 2 * WW);
  }

#pragma unroll 2
  for (int h = 0; h < HH; ++h) {
    float4 xn = neg4;
    if (h + 3 < HH && act)
      xn = *(const float4*)(cp + (size_t)(h + 3) * WW);

    float4 xv;
    if (PRE) {
      xv = xa;  // already log2(1+relu) form; inactive lanes stay NEGF
    } else {
      xv.x = act ? __log2f(1.0f + fmaxf(xa.x, 0.0f)) : NEGF;
      xv.y = act ? __log2f(1.0f + fmaxf(xa.y, 0.0f)) : NEGF;
      xv.z = act ? __log2f(1.0f + fmaxf(xa.z, 0.0f)) : NEGF;
      xv.w = act ? __log2f(1.0f + fmaxf(xa.w, 0.0f)) : NEGF;
    }

    // s_j(w) = M_j(h-1, w-1); -inf enters at col 0 via wshr1.
    float b1 = wshr1(pm1.w), b2 = wshr1(pm2.w), b3 = wshr1(pm3.w), b4 = wshr1(pm4.w);
    float4 s1 = make_float4(b1, pm1.x, pm1.y, pm1.z);
    float4 s2 = make_float4(b2, pm2.x, pm2.y, pm2.z);
    float4 s3 = make_float4(b3, pm3.x, pm3.y, pm3.z);
    float4 s4 = make_float4(b4, pm4.x, pm4.y, pm4.z);

    float4 v0 = xv, v1 = xv, v2 = xv, v3 = xv, v4 = xv;
    (void)v4;

    if      (p4 == 0) ADD4(v0, s4) else if (p4 == 1) ADD4(v1, s4)
    else if (p4 == 2) ADD4(v2, s4) else              ADD4(v3, s4);
    if      (p3 == 0) ADD4(v0, s3) else if (p3 == 1) ADD4(v1, s3)
    else              ADD4(v2, s3);
    if      (p2 == 0) ADD4(v0, s2) else              ADD4(v1, s2);
    ADD4(v0, s1);  // p1 == 0 always

    // Local (within-lane) prefix maxes.
    float l10 = v1.x, l11 = fmaxf(l10, v1.y), l12 = fmaxf(l11, v1.z);
    float l20 = v2.x, l21 = fmaxf(l20, v2.y), l22 = fmaxf(l21, v2.z);
    float l30 = v3.x, l31 = fmaxf(l30, v3.y), l32 = fmaxf(l31, v3.z);
    float l40 = v4.x, l41 = fmaxf(l40, v4.y), l42 = fmaxf(l41, v4.z);
    float q1 = fmaxf(l12, v1.w);
    float q2 = fmaxf(l22, v2.w);
    float q3 = fmaxf(l32, v3.w);
    float q4 = fmaxf(l42, v4.w);

    // Wave-level inclusive max-scan, 6 stages x 4 nodes, stage-major.
    DPP_FENCE(q1, q2, q3, q4);
    SCAN_SHR(q1, 1); SCAN_SHR(q2, 1); SCAN_SHR(q3, 1); SCAN_SHR(q4, 1);
    SCAN_SHR(q1, 2); SCAN_SHR(q2, 2); SCAN_SHR(q3, 2); SCAN_SHR(q4, 2);
    SCAN_SHR(q1, 4); SCAN_SHR(q2, 4); SCAN_SHR(q3, 4); SCAN_SHR(q4, 4);
    SCAN_SHR(q1, 8); SCAN_SHR(q2, 8); SCAN_SHR(q3, 8); SCAN_SHR(q4, 8);
    SCAN_B15(q1);    SCAN_B15(q2);    SCAN_B15(q3);    SCAN_B15(q4);
    SCAN_B31(q1);    SCAN_B31(q2);    SCAN_B31(q3);    SCAN_B31(q4);
    DPP_FENCE(q1, q2, q3, q4);

    float e1 = wshr1(q1), e2 = wshr1(q2), e3 = wshr1(q3), e4 = wshr1(q4);

    // pm = max(pm, e, local) — v_max3_f32 pattern.
    pm1.x = fmaxf(fmaxf(e1, l10), pm1.x);
    pm1.y = fmaxf(fmaxf(e1, l11), pm1.y);
    pm1.z = fmaxf(fmaxf(e1, l12), pm1.z);
    pm1.w = fmaxf(q1, pm1.w);
    pm2.x = fmaxf(fmaxf(e2, l20), pm2.x);
    pm2.y = fmaxf(fmaxf(e2, l21), pm2.y);
    pm2.z = fmaxf(fmaxf(e2, l22), pm2.z);
    pm2.w = fmaxf(q2, pm2.w);
    pm3.x = fmaxf(fmaxf(e3, l30), pm3.x);
    pm3.y = fmaxf(fmaxf(e3, l31), pm3.y);
    pm3.z = fmaxf(fmaxf(e3, l32), pm3.z);
    pm3.w = fmaxf(q3, pm3.w);
    pm4.x = fmaxf(fmaxf(e4, l40), pm4.x);
    pm4.y = fmaxf(fmaxf(e4, l41), pm4.y);
    pm4.z = fmaxf(fmaxf(e4, l42), pm4.z);
    pm4.w = fmaxf(q4, pm4.w);

    racc.x = fmaxf(racc.x, v0.x);
    racc.y = fmaxf(racc.y, v0.y);
    racc.z = fmaxf(racc.z, v0.z);
    racc.w = fmaxf(racc.w, v0.w);

    xa = xb; xb = xc; xc = xn;
  }

  float m = fmaxf(fmaxf(racc.x, racc.y), fmaxf(racc.z, racc.w));
#pragma unroll
  for (int d = 1; d < 64; d <<= 1) m = fmaxf(m, __shfl_xor(m, d));
  if (lane == 0)
    out[((size_t)b * NTREES + t) * CC + c] = expm1f(fmaf(m, LN2F, asum));
}

extern "C" void kernel_launch(void* const* d_in, const int* in_sizes, int n_in,
                              void* d_out, int out_size, void* d_ws, size_t ws_size,
                              hipStream_t stream) {
  const float* x      = (const float*)d_in[0];
  const float* alphas = (const float*)d_in[1];
  float* out          = (float*)d_out;

  Forest f;
  nprng::make_forest(f);  // deterministic; same every call (graph-capture safe)

  const size_t need = (size_t)BB * CC * HH * WW * sizeof(float);
  dim3 grid(BB * CC * NTREES);
  dim3 block(64);

  if (ws_size >= need) {
    const int n4 = (BB * CC * HH * WW) / 4;
    hipLaunchKernelGGL(xv_kernel, dim3((n4 + 255) / 256), dim3(256), 0, stream,
                       x, (float*)d_ws, n4);
    hipLaunchKernelGGL(fis_kernel<true>, grid, block, 0, stream,
                       (const float*)d_ws, alphas, out, f);
  } else {
    hipLaunchKernelGGL(fis_kernel<false>, grid, block, 0, stream,
                       x, alphas, out, f);
  }
}